// Round 4
// baseline (485.259 us; speedup 1.0000x reference)
//
#include <hip/hip_runtime.h>

// Problem dims (fixed by reference setup_inputs)
#define N_DOCS   4096
#define N_WORDS  10000
#define N_TOPICS 100
#define EDIM     384
#define KPAD     128       // padded inner dim for bf16 MFMA recon
#define BT_ROWS  10112     // beta^T rows allocated (79*128 grid cols)
#define RECON_BLOCKS (79 * 32)

// ---------------- workspace layout (float offsets) --------------------------------
// [0..8): 4 doubles: loss_DT, loss_TW, sum(bow*log(recon)), unused
// fws[8]: err_dt, fws[9]: err_tw, ((int*)fws)[10]: recon completion counter
#define OFF_KDT   16u                        // 4096*100 fp32
#define OFF_KDTT  (OFF_KDT  + 409600u)       // 100*4096 fp32 (transpose)
#define OFF_KTW   (OFF_KDTT + 409600u)       // 100*10000 fp32
#define OFF_BDT   (OFF_KTW  + 1000000u)      // 100 (pad 128)
#define OFF_BTW   (OFF_BDT  + 128u)          // 10000 (pad 10016)
#define OFF_ND    (OFF_BTW  + 10016u)        // 4096
#define OFF_NW    (OFF_ND   + 4096u)         // 10000 (pad 10016)
#define OFF_NT    (OFF_NW   + 10016u)        // 100 (pad 128)
#define OFF_UDT   (OFF_NT   + 128u)          // 4096
#define OFF_VDT   (OFF_UDT  + 4096u)         // 100 (pad 128)
#define OFF_UTW   (OFF_VDT  + 128u)          // 100 (pad 128)
#define OFF_VTW   (OFF_UTW  + 128u)          // 10000 (pad 10016)
#define OFF_THB   (OFF_VTW  + 10016u)        // theta bf16 4096*128 = 262144 floats
#define OFF_BTT   (OFF_THB  + 262144u)       // beta^T bf16 10112*128 = 647168 floats

typedef __attribute__((ext_vector_type(8))) short bf16x8;
typedef __attribute__((ext_vector_type(4))) float f32x4;

__device__ __forceinline__ float block_reduce_sum_256(float v, volatile float* sh) {
#pragma unroll
  for (int off = 32; off > 0; off >>= 1) v += __shfl_down(v, off, 64);
  __syncthreads();
  if ((threadIdx.x & 63) == 0) sh[threadIdx.x >> 6] = v;
  __syncthreads();
  return sh[0] + sh[1] + sh[2] + sh[3];
}

__device__ __forceinline__ float block_reduce_sum_1024(float v, volatile float* sh) {
#pragma unroll
  for (int off = 32; off > 0; off >>= 1) v += __shfl_down(v, off, 64);
  if ((threadIdx.x & 63) == 0) sh[threadIdx.x >> 6] = v;
  __syncthreads();
  if (threadIdx.x == 0) {
    float s = 0.f;
    for (int i = 0; i < 16; ++i) s += sh[i];
    sh[16] = s;
  }
  __syncthreads();
  float r = sh[16];
  __syncthreads();
  return r;
}

__device__ __forceinline__ float block_reduce_max_1024(float v, volatile float* sh) {
#pragma unroll
  for (int off = 32; off > 0; off >>= 1) v = fmaxf(v, __shfl_down(v, off, 64));
  if ((threadIdx.x & 63) == 0) sh[threadIdx.x >> 6] = v;
  __syncthreads();
  if (threadIdx.x == 0) {
    float m = sh[0];
    for (int i = 1; i < 16; ++i) m = fmaxf(m, sh[i]);
    sh[16] = m;
  }
  __syncthreads();
  float r = sh[16];
  __syncthreads();
  return r;
}

__device__ __forceinline__ unsigned short f2bf(float x) {
  union { float f; unsigned int u; } c; c.f = x;
  unsigned int r = c.u + 0x7FFF + ((c.u >> 16) & 1);   // RNE
  return (unsigned short)(r >> 16);
}

// ========== K1: norms (blocks 0..887) + softmaxes/zeroing (block 888) ==============
__global__ __launch_bounds__(1024)
void prep_norms_kernel(const float* __restrict__ docs, const float* __restrict__ words,
                       const float* __restrict__ topics,
                       const float* __restrict__ topic_w, const float* __restrict__ word_w,
                       float* __restrict__ nd, float* __restrict__ nw, float* __restrict__ nt,
                       float* __restrict__ b_dt, float* __restrict__ b_tw,
                       double* __restrict__ dscal, float* __restrict__ errs,
                       int* __restrict__ counter) {
  int tid = threadIdx.x, lane = tid & 63, wave = tid >> 6;
  if (blockIdx.x < 888) {   // row norms: 16 rows/block, one wave per row
    int row = blockIdx.x * 16 + wave;
    if (row < N_DOCS + N_WORDS + N_TOPICS) {
      const float* src; float* dst; int r;
      if (row < N_DOCS)                { src = docs;   r = row;                    dst = nd; }
      else if (row < N_DOCS + N_WORDS) { src = words;  r = row - N_DOCS;           dst = nw; }
      else                             { src = topics; r = row - N_DOCS - N_WORDS; dst = nt; }
      float s = 0.f;
#pragma unroll
      for (int k = lane; k < EDIM; k += 64) { float x = src[r * EDIM + k]; s += x * x; }
#pragma unroll
      for (int off = 32; off > 0; off >>= 1) s += __shfl_down(s, off, 64);
      if (lane == 0) dst[r] = s;
    }
    return;
  }
  // prep block
  __shared__ float sh[20];
  // topic softmax (100)
  float m = (tid < N_TOPICS) ? topic_w[tid] : -3.0e38f;
  m = block_reduce_max_1024(m, sh);
  float e = (tid < N_TOPICS) ? __expf(topic_w[tid] - m) : 0.f;
  float s = block_reduce_sum_1024(e, sh);
  if (tid < N_TOPICS) b_dt[tid] = e / s;
  // word softmax (10000), float4 vectorized
  float m2 = -3.0e38f;
  for (int i = tid * 4; i < N_WORDS; i += 4096) {
    float4 w = *reinterpret_cast<const float4*>(&word_w[i]);
    m2 = fmaxf(fmaxf(m2, fmaxf(w.x, w.y)), fmaxf(w.z, w.w));
  }
  m2 = block_reduce_max_1024(m2, sh);
  float s2 = 0.f;
  for (int i = tid * 4; i < N_WORDS; i += 4096) {
    float4 w = *reinterpret_cast<const float4*>(&word_w[i]);
    s2 += __expf(w.x - m2) + __expf(w.y - m2) + __expf(w.z - m2) + __expf(w.w - m2);
  }
  s2 = block_reduce_sum_1024(s2, sh);
  float inv2 = 1.0f / s2;
  for (int i = tid * 4; i < N_WORDS; i += 4096) {
    float4 w = *reinterpret_cast<const float4*>(&word_w[i]);
    float4 o = make_float4(__expf(w.x - m2) * inv2, __expf(w.y - m2) * inv2,
                           __expf(w.z - m2) * inv2, __expf(w.w - m2) * inv2);
    *reinterpret_cast<float4*>(&b_tw[i]) = o;
  }
  if (tid < 4) dscal[tid] = 0.0;
  if (tid < 2) errs[tid] = 0.f;
  if (tid == 0) *counter = 0;
}

// ========== K2: both distance kernels K = exp(-alpha*dist) =========================
__global__ __launch_bounds__(256)
void dist_kernel(const float* __restrict__ docs, const float* __restrict__ words,
                 const float* __restrict__ topics,
                 const float* __restrict__ nd, const float* __restrict__ nw,
                 const float* __restrict__ nt,
                 float* __restrict__ Kdt, float* __restrict__ KdtT,
                 float* __restrict__ Ktw) {
  __shared__ __align__(16) float As[16][64];
  __shared__ __align__(16) float Bs[16][64];
  const int bid = blockIdx.x;
  const float *A, *B, *nA, *nB; float *Kout, *KoutT; int nI, nJ, i0, j0; float alpha;
  if (bid < 128) {      // doc-topic: 64 i-tiles x 2 j-tiles
    A = docs; B = topics; nA = nd; nB = nt; Kout = Kdt; KoutT = KdtT;
    nI = N_DOCS; nJ = N_TOPICS; alpha = 3.0f;
    j0 = (bid & 1) * 64; i0 = (bid >> 1) * 64;
  } else {              // topic-word: 2 i-tiles x 157 j-tiles
    int b2 = bid - 128;
    A = topics; B = words; nA = nt; nB = nw; Kout = Ktw; KoutT = nullptr;
    nI = N_TOPICS; nJ = N_WORDS; alpha = 2.0f;
    i0 = (b2 & 1) * 64; j0 = (b2 >> 1) * 64;
  }
  const int tid = threadIdx.x;
  const int r = tid & 63, kg = tid >> 6;
  const int tx = tid & 15, ty = tid >> 4;
  float acc[4][4] = {};
  for (int k0 = 0; k0 < EDIM; k0 += 16) {
    float4 av = make_float4(0.f, 0.f, 0.f, 0.f);
    float4 bv = make_float4(0.f, 0.f, 0.f, 0.f);
    int gi = i0 + r, gj = j0 + r;
    if (gi < nI) av = *reinterpret_cast<const float4*>(&A[gi * EDIM + k0 + kg * 4]);
    if (gj < nJ) bv = *reinterpret_cast<const float4*>(&B[gj * EDIM + k0 + kg * 4]);
    As[kg * 4 + 0][r] = av.x; As[kg * 4 + 1][r] = av.y;
    As[kg * 4 + 2][r] = av.z; As[kg * 4 + 3][r] = av.w;
    Bs[kg * 4 + 0][r] = bv.x; Bs[kg * 4 + 1][r] = bv.y;
    Bs[kg * 4 + 2][r] = bv.z; Bs[kg * 4 + 3][r] = bv.w;
    __syncthreads();
#pragma unroll
    for (int kk = 0; kk < 16; ++kk) {
      float4 a4 = *reinterpret_cast<const float4*>(&As[kk][ty * 4]);
      float4 b4 = *reinterpret_cast<const float4*>(&Bs[kk][tx * 4]);
      float aa[4] = {a4.x, a4.y, a4.z, a4.w};
      float bb[4] = {b4.x, b4.y, b4.z, b4.w};
#pragma unroll
      for (int di = 0; di < 4; ++di)
#pragma unroll
        for (int dj = 0; dj < 4; ++dj) acc[di][dj] += aa[di] * bb[dj];
    }
    __syncthreads();
  }
#pragma unroll
  for (int di = 0; di < 4; ++di) {
    int gi = i0 + ty * 4 + di;
    if (gi < nI) {
      float na = nA[gi];
#pragma unroll
      for (int dj = 0; dj < 4; ++dj) {
        int gj = j0 + tx * 4 + dj;
        if (gj < nJ) {
          float val = __expf(-alpha * (na + nB[gj] - 2.f * acc[di][dj]));
          Kout[(size_t)gi * nJ + gj] = val;
          if (KoutT) KoutT[(size_t)gj * nI + gi] = val;
        }
      }
    }
  }
}

// ========== K3: colsum -> v for both transports ====================================
__global__ __launch_bounds__(256)
void cs_kernel(const float* __restrict__ KdtT, const float* __restrict__ b_dt,
               float* __restrict__ v_dt,
               const float* __restrict__ Ktw, const float* __restrict__ b_tw,
               float* __restrict__ v_tw) {
  __shared__ float sh[4];
  const int tid = threadIdx.x;
  if (blockIdx.x < 100) {          // DT: one block per topic column
    int j = blockIdx.x;
    float s = 0.f;
#pragma unroll 8
    for (int i = tid; i < N_DOCS; i += 256) s += KdtT[(size_t)j * N_DOCS + i];
    s = block_reduce_sum_256(s, sh);
    if (tid == 0) v_dt[j] = b_dt[j] / (s * (1.0f / N_DOCS) + 1e-16f);
  } else {                          // TW: one thread per word column
    int j = (blockIdx.x - 100) * 256 + tid;
    if (j < N_WORDS) {
      float s = 0.f;
#pragma unroll 10
      for (int i = 0; i < N_TOPICS; ++i) s += Ktw[(size_t)i * N_WORDS + j];
      v_tw[j] = b_tw[j] / (s * 0.01f + 1e-16f);
    }
  }
}

// ========== K4: rowdot -> u for both transports ====================================
__global__ __launch_bounds__(256)
void u_kernel(const float* __restrict__ Kdt, const float* __restrict__ v_dt,
              float* __restrict__ u_dt,
              const float* __restrict__ Ktw, const float* __restrict__ v_tw,
              float* __restrict__ u_tw) {
  __shared__ float vl[N_TOPICS];
  __shared__ float sh[4];
  const int tid = threadIdx.x;
  if (blockIdx.x < 16) {            // DT: one thread per doc row
    if (tid < N_TOPICS) vl[tid] = v_dt[tid];
    __syncthreads();
    int i = blockIdx.x * 256 + tid;
    float d = 0.f;
    const float* row = &Kdt[(size_t)i * N_TOPICS];
#pragma unroll
    for (int j4 = 0; j4 < N_TOPICS; j4 += 4) {
      float4 kv = *reinterpret_cast<const float4*>(&row[j4]);
      d += kv.x * vl[j4] + kv.y * vl[j4 + 1] + kv.z * vl[j4 + 2] + kv.w * vl[j4 + 3];
    }
    u_dt[i] = (1.0f / N_DOCS) / (d + 1e-16f);
  } else {                          // TW: one block per topic row
    int i = blockIdx.x - 16;
    float d = 0.f;
    const float* row = &Ktw[(size_t)i * N_WORDS];
    for (int j = tid * 4; j < N_WORDS; j += 1024) {
      float4 kv = *reinterpret_cast<const float4*>(&row[j]);
      float4 vv = *reinterpret_cast<const float4*>(&v_tw[j]);
      d += kv.x * vv.x + kv.y * vv.y + kv.z * vv.z + kv.w * vv.w;
    }
    d = block_reduce_sum_256(d, sh);
    if (tid == 0) u_tw[i] = 0.01f / (d + 1e-16f);
  }
}

// ========== K5: convergence error for both transports ==============================
__global__ __launch_bounds__(256)
void err_kernel(const float* __restrict__ KdtT, const float* __restrict__ u_dt,
                const float* __restrict__ v_dt, const float* __restrict__ b_dt,
                const float* __restrict__ Ktw, const float* __restrict__ u_tw,
                const float* __restrict__ v_tw, const float* __restrict__ b_tw,
                float* __restrict__ errs) {
  __shared__ float sh[4];
  __shared__ float ul[N_TOPICS];
  const int tid = threadIdx.x;
  if (blockIdx.x < 100) {
    int j = blockIdx.x;
    float s = 0.f;
#pragma unroll 8
    for (int i = tid; i < N_DOCS; i += 256) s += KdtT[(size_t)j * N_DOCS + i] * u_dt[i];
    s = block_reduce_sum_256(s, sh);
    if (tid == 0) atomicAdd(&errs[0], fabsf(v_dt[j] * s - b_dt[j]));
  } else {
    if (tid < N_TOPICS) ul[tid] = u_tw[tid];
    __syncthreads();
    int j = (blockIdx.x - 100) * 256 + tid;
    float e = 0.f;
    if (j < N_WORDS) {
      float s = 0.f;
#pragma unroll 10
      for (int i = 0; i < N_TOPICS; ++i) s += Ktw[(size_t)i * N_WORDS + j] * ul[i];
      e = fabsf(v_tw[j] * s - b_tw[j]);
    }
    e = block_reduce_sum_256(e, sh);
    if (tid == 0) atomicAdd(&errs[1], e);
  }
}

// ========== K6: faithful remainder loops (exit immediately when converged) =========
__global__ __launch_bounds__(1024)
void rem_kernel(const float* __restrict__ Kdt, const float* __restrict__ KdtT,
                const float* __restrict__ b_dt, float* __restrict__ u_dt,
                float* __restrict__ v_dt,
                const float* __restrict__ Ktw, const float* __restrict__ b_tw,
                float* __restrict__ u_tw, float* __restrict__ v_tw,
                const float* __restrict__ errs) {
  __shared__ float rsm[20104];     // 80.4 KB, partitioned per branch
  const int tid = threadIdx.x, wave = tid >> 6, lane = tid & 63;
  if (blockIdx.x == 0) {           // DT remainder
    float err = errs[0];
    if (!(err > 0.005f)) return;
    float* u_l = rsm; float* v_l = rsm + 4096; float* bl = rsm + 4196; float* esh = rsm + 4296;
    for (int i = tid; i < N_DOCS; i += 1024) u_l[i] = u_dt[i];
    if (tid < N_TOPICS) { bl[tid] = b_dt[tid]; v_l[tid] = v_dt[tid]; }
    __syncthreads();
    int cpt = 1;
    while (err > 0.005f && cpt < 5000) {
      for (int j = wave; j < N_TOPICS; j += 16) {
        float s = 0.f;
        for (int i = lane; i < N_DOCS; i += 64) s += KdtT[(size_t)j * N_DOCS + i] * u_l[i];
#pragma unroll
        for (int off = 32; off > 0; off >>= 1) s += __shfl_down(s, off, 64);
        if (lane == 0) v_l[j] = bl[j] / (s + 1e-16f);
      }
      __syncthreads();
      for (int i = tid; i < N_DOCS; i += 1024) {
        float d = 0.f;
        for (int j = 0; j < N_TOPICS; ++j) d += Kdt[(size_t)i * N_TOPICS + j] * v_l[j];
        u_l[i] = (1.0f / N_DOCS) / (d + 1e-16f);
      }
      __syncthreads();
      ++cpt;
      if (cpt % 50 == 1) {
        if (tid == 0) *esh = 0.f;
        __syncthreads();
        for (int j = wave; j < N_TOPICS; j += 16) {
          float s = 0.f;
          for (int i = lane; i < N_DOCS; i += 64) s += KdtT[(size_t)j * N_DOCS + i] * u_l[i];
#pragma unroll
          for (int off = 32; off > 0; off >>= 1) s += __shfl_down(s, off, 64);
          if (lane == 0) atomicAdd(esh, fabsf(v_l[j] * s - bl[j]));
        }
        __syncthreads();
        err = *esh;
        __syncthreads();
      }
    }
    for (int i = tid; i < N_DOCS; i += 1024) u_dt[i] = u_l[i];
    if (tid < N_TOPICS) v_dt[tid] = v_l[tid];
  } else {                          // TW remainder
    float err = errs[1];
    if (!(err > 0.005f)) return;
    float* v_l = rsm; float* bl = rsm + 10000; float* u_l = rsm + 20000; float* esh = rsm + 20100;
    for (int j = tid; j < N_WORDS; j += 1024) { v_l[j] = v_tw[j]; bl[j] = b_tw[j]; }
    if (tid < N_TOPICS) u_l[tid] = u_tw[tid];
    __syncthreads();
    int cpt = 1;
    while (err > 0.005f && cpt < 5000) {
      for (int j = tid; j < N_WORDS; j += 1024) {
        float s = 0.f;
        for (int i = 0; i < N_TOPICS; ++i) s += Ktw[(size_t)i * N_WORDS + j] * u_l[i];
        v_l[j] = bl[j] / (s + 1e-16f);
      }
      __syncthreads();
      for (int i = wave; i < N_TOPICS; i += 16) {
        float s = 0.f;
        for (int j = lane; j < N_WORDS; j += 64) s += Ktw[(size_t)i * N_WORDS + j] * v_l[j];
#pragma unroll
        for (int off = 32; off > 0; off >>= 1) s += __shfl_down(s, off, 64);
        if (lane == 0) u_l[i] = 0.01f / (s + 1e-16f);
      }
      __syncthreads();
      ++cpt;
      if (cpt % 50 == 1) {
        if (tid == 0) *esh = 0.f;
        __syncthreads();
        float e = 0.f;
        for (int j = tid; j < N_WORDS; j += 1024) {
          float s = 0.f;
          for (int i = 0; i < N_TOPICS; ++i) s += Ktw[(size_t)i * N_WORDS + j] * u_l[i];
          e += fabsf(v_l[j] * s - bl[j]);
        }
        atomicAdd(esh, e);
        __syncthreads();
        err = *esh;
        __syncthreads();
      }
    }
    for (int j = tid; j < N_WORDS; j += 1024) v_tw[j] = v_l[j];
    if (tid < N_TOPICS) u_tw[tid] = u_l[tid];
  }
}

// ========== K7: theta/beta^T (bf16, K-padded) + transport losses ===================
__global__ __launch_bounds__(256)
void apply_kernel(const float* __restrict__ Kdt, const float* __restrict__ u_dt,
                  const float* __restrict__ v_dt,
                  const float* __restrict__ Ktw, const float* __restrict__ u_tw,
                  const float* __restrict__ v_tw,
                  unsigned short* __restrict__ theta_b, unsigned short* __restrict__ beta_bT,
                  double* __restrict__ dscal) {
  __shared__ float sh[4];
  __shared__ float ul[N_TOPICS];
  const int tid = threadIdx.x;
  if (blockIdx.x < 2048) {          // theta: 4096*128 elements
    int idx = blockIdx.x * 256 + tid;
    int i = idx >> 7, k = idx & 127;
    float lp = 0.f;
    unsigned short o = 0;
    if (k < N_TOPICS) {
      float kv = Kdt[(size_t)i * N_TOPICS + k];
      float t = u_dt[i] * kv * v_dt[k];
      lp = t * (-__logf(kv) * (1.0f / 3.0f));
      o = f2bf(t * (float)N_DOCS);
    }
    theta_b[idx] = o;
    lp = block_reduce_sum_256(lp, sh);
    if (tid == 0) atomicAdd(&dscal[0], (double)lp);
  } else {                          // beta^T rows
    if (tid < N_TOPICS) ul[tid] = u_tw[tid];
    __syncthreads();
    int n = (blockIdx.x - 2048) * 256 + tid;
    float lp = 0.f;
    if (n < N_WORDS) {
      float vn = v_tw[n];
      unsigned short* dst = &beta_bT[(size_t)n * KPAD];
#pragma unroll 2
      for (int kc = 0; kc < KPAD; kc += 8) {
        unsigned short pk[8];
#pragma unroll
        for (int q = 0; q < 8; ++q) {
          int k = kc + q;
          unsigned short o = 0;
          if (k < N_TOPICS) {
            float kv = Ktw[(size_t)k * N_WORDS + n];
            float t = ul[k] * kv * vn;
            lp += t * (-__logf(kv) * 0.5f);
            o = f2bf(t * (float)N_TOPICS);
          }
          pk[q] = o;
        }
        *(uint4*)&dst[kc] = *(uint4*)pk;
      }
    } else if (n < BT_ROWS) {       // zero the pad rows so recon stays clean
      unsigned short* dst = &beta_bT[(size_t)n * KPAD];
      uint4 z = make_uint4(0, 0, 0, 0);
#pragma unroll
      for (int kc = 0; kc < KPAD; kc += 8) *(uint4*)&dst[kc] = z;
    }
    lp = block_reduce_sum_256(lp, sh);
    if (tid == 0) atomicAdd(&dscal[1], (double)lp);
  }
}

// ========== K8: recon via bf16 MFMA; bow prefetched into regs at kernel start ======
#define AS_LD 136   // staging LD (bf16): 2-way conflicts only
#define CLD   132   // acc tile LD (fp32): float4-aligned
__global__ __launch_bounds__(256, 2)
void recon_kernel(const unsigned short* __restrict__ theta_b,
                  const unsigned short* __restrict__ beta_bT,
                  const float* __restrict__ bow, double* __restrict__ dscal,
                  int* __restrict__ counter, float* __restrict__ out) {
  __shared__ __align__(16) char smem[128 * AS_LD * 2 * 2];  // 69632 B, reused for C tile
  __shared__ float sh4[4];
  unsigned short* As = (unsigned short*)smem;
  unsigned short* Bs = As + 128 * AS_LD;
  float* C = (float*)smem;          // 128 x CLD fp32 = 67584 B <= 69632
  const int tid = threadIdx.x;
  const int c0 = blockIdx.x * 128, r0 = blockIdx.y * 128;

  // ---- bow prefetch: 16 independent float4 loads issued before any barrier ----
  const int c4 = tid & 31;          // float4 column 0..31
  const int rb = tid >> 5;          // row base 0..7
  const int gj0 = c0 + c4 * 4;
  const bool jok = (gj0 < N_WORDS); // N_WORDS%4==0 -> full float4 valid when true
  float4 bw[16];
  if (jok) {
#pragma unroll
    for (int it = 0; it < 16; ++it)
      bw[it] = *reinterpret_cast<const float4*>(&bow[(size_t)(r0 + rb + it * 8) * N_WORDS + gj0]);
  }

  // ---- stage theta/beta tiles into LDS ----
#pragma unroll
  for (int pass = 0; pass < 8; ++pass) {
    int idx = pass * 256 + tid;     // 0..2047
    int r = idx >> 4, k16 = idx & 15;
    *(uint4*)&As[r * AS_LD + k16 * 8] = *(const uint4*)&theta_b[(size_t)(r0 + r) * KPAD + k16 * 8];
    *(uint4*)&Bs[r * AS_LD + k16 * 8] = *(const uint4*)&beta_bT[(size_t)(c0 + r) * KPAD + k16 * 8];
  }
  __syncthreads();

  // ---- MFMA: 128x128 tile, 4 waves, 4x4 fragments each ----
  const int wave = tid >> 6, lane = tid & 63;
  const int wr = (wave >> 1) * 64, wc = (wave & 1) * 64;
  const int lm = lane & 15, q = lane >> 4;
  f32x4 acc[4][4] = {};
#pragma unroll
  for (int kc = 0; kc < 4; ++kc) {
    int k = kc * 32 + q * 8;
    bf16x8 af[4], bfr[4];
#pragma unroll
    for (int t = 0; t < 4; ++t) {
      af[t]  = *(const bf16x8*)&As[(wr + t * 16 + lm) * AS_LD + k];
      bfr[t] = *(const bf16x8*)&Bs[(wc + t * 16 + lm) * AS_LD + k];
    }
#pragma unroll
    for (int mi = 0; mi < 4; ++mi)
#pragma unroll
      for (int ni = 0; ni < 4; ++ni)
        acc[mi][ni] = __builtin_amdgcn_mfma_f32_16x16x32_bf16(af[mi], bfr[ni],
                                                              acc[mi][ni], 0, 0, 0);
  }
  __syncthreads();                  // A/B consumed; reuse smem for C tile

  // ---- scatter acc (MFMA C layout) into fp32 LDS tile ----
#pragma unroll
  for (int mi = 0; mi < 4; ++mi)
#pragma unroll
    for (int ni = 0; ni < 4; ++ni)
#pragma unroll
      for (int reg = 0; reg < 4; ++reg) {
        int row = wr + mi * 16 + q * 4 + reg;
        int col = wc + ni * 16 + lm;
        C[row * CLD + col] = acc[mi][ni][reg];
      }
  __syncthreads();

  // ---- batched LDS readback + log/dot epilogue (bow already in registers) ----
  float lp = 0.f;
  if (jok) {
    float4 rc[16];
#pragma unroll
    for (int it = 0; it < 16; ++it)
      rc[it] = *reinterpret_cast<const float4*>(&C[(rb + it * 8) * CLD + c4 * 4]);
#pragma unroll
    for (int it = 0; it < 16; ++it) {
      lp += bw[it].x * __logf(rc[it].x + 1e-12f) + bw[it].y * __logf(rc[it].y + 1e-12f)
          + bw[it].z * __logf(rc[it].z + 1e-12f) + bw[it].w * __logf(rc[it].w + 1e-12f);
    }
  }
  lp = block_reduce_sum_256(lp, sh4);
  if (tid == 0) {
    atomicAdd(&dscal[2], (double)lp);
    __threadfence();
    int done = atomicAdd(counter, 1);
    if (done == RECON_BLOCKS - 1) { // last block finalizes
      double s2 = atomicAdd(&dscal[2], 0.0);
      double s0 = atomicAdd(&dscal[0], 0.0);
      double s1 = atomicAdd(&dscal[1], 0.0);
      out[0] = (float)(s0 + s1 - s2 * (1.0 / N_DOCS));
    }
  }
}

extern "C" void kernel_launch(void* const* d_in, const int* in_sizes, int n_in,
                              void* d_out, int out_size, void* d_ws, size_t ws_size,
                              hipStream_t stream) {
  const float* bow     = (const float*)d_in[0];
  const float* docs    = (const float*)d_in[1];
  const float* words   = (const float*)d_in[2];
  const float* topics  = (const float*)d_in[3];
  const float* word_w  = (const float*)d_in[4];
  const float* topic_w = (const float*)d_in[5];
  float* out = (float*)d_out;

  double* dscal = (double*)d_ws;
  float* fws  = (float*)d_ws;
  float* errs = fws + 8;
  int* counter = ((int*)d_ws) + 10;
  float* Kdt  = fws + OFF_KDT;
  float* KdtT = fws + OFF_KDTT;
  float* Ktw  = fws + OFF_KTW;
  float* b_dt = fws + OFF_BDT;
  float* b_tw = fws + OFF_BTW;
  float* nd   = fws + OFF_ND;
  float* nw   = fws + OFF_NW;
  float* nt   = fws + OFF_NT;
  float* u_dt = fws + OFF_UDT;
  float* v_dt = fws + OFF_VDT;
  float* u_tw = fws + OFF_UTW;
  float* v_tw = fws + OFF_VTW;
  unsigned short* theta_b = (unsigned short*)(fws + OFF_THB);
  unsigned short* beta_bT = (unsigned short*)(fws + OFF_BTT);

  prep_norms_kernel<<<dim3(889), dim3(1024), 0, stream>>>(
      docs, words, topics, topic_w, word_w, nd, nw, nt, b_dt, b_tw, dscal, errs, counter);
  dist_kernel<<<dim3(442), dim3(256), 0, stream>>>(
      docs, words, topics, nd, nw, nt, Kdt, KdtT, Ktw);
  cs_kernel<<<dim3(140), dim3(256), 0, stream>>>(KdtT, b_dt, v_dt, Ktw, b_tw, v_tw);
  u_kernel<<<dim3(116), dim3(256), 0, stream>>>(Kdt, v_dt, u_dt, Ktw, v_tw, u_tw);
  err_kernel<<<dim3(140), dim3(256), 0, stream>>>(
      KdtT, u_dt, v_dt, b_dt, Ktw, u_tw, v_tw, b_tw, errs);
  rem_kernel<<<dim3(2), dim3(1024), 0, stream>>>(
      Kdt, KdtT, b_dt, u_dt, v_dt, Ktw, b_tw, u_tw, v_tw, errs);
  apply_kernel<<<dim3(2088), dim3(256), 0, stream>>>(
      Kdt, u_dt, v_dt, Ktw, u_tw, v_tw, theta_b, beta_bT, dscal);
  recon_kernel<<<dim3(79, 32), dim3(256), 0, stream>>>(
      theta_b, beta_bT, bow, dscal, counter, out);

  (void)in_sizes; (void)n_in; (void)out_size; (void)ws_size;
}

// Round 5
// 368.435 us; speedup vs baseline: 1.3171x; 1.3171x over previous
//
#include <hip/hip_runtime.h>

// Problem dims (fixed by reference setup_inputs)
#define N_DOCS   4096
#define N_WORDS  10000
#define N_TOPICS 100
#define EDIM     384
#define KPAD     128       // padded inner dim for bf16 MFMA recon
#define BT_ROWS  10112     // beta^T rows allocated (79*128 grid cols)
#define RECON_BLOCKS (79 * 32)
#define APPLY_BLOCKS 2088

// ---------------- workspace layout (float offsets) --------------------------------
// fws[8]: err_dt, fws[9]: err_tw
#define OFF_KDT   16u                        // 4096*100 fp32
#define OFF_KDTT  (OFF_KDT  + 409600u)       // 100*4096 fp32 (transpose)
#define OFF_KTW   (OFF_KDTT + 409600u)       // 100*10000 fp32
#define OFF_BDT   (OFF_KTW  + 1000000u)      // 100 (pad 128)
#define OFF_BTW   (OFF_BDT  + 128u)          // 10000 (pad 10016)
#define OFF_ND    (OFF_BTW  + 10016u)        // 4096
#define OFF_NW    (OFF_ND   + 4096u)         // 10000 (pad 10016)
#define OFF_NT    (OFF_NW   + 10016u)        // 100 (pad 128)
#define OFF_UDT   (OFF_NT   + 128u)          // 4096
#define OFF_VDT   (OFF_UDT  + 4096u)         // 100 (pad 128)
#define OFF_UTW   (OFF_VDT  + 128u)          // 100 (pad 128)
#define OFF_VTW   (OFF_UTW  + 128u)          // 10000 (pad 10016)
#define OFF_THB   (OFF_VTW  + 10016u)        // theta bf16 4096*128 = 262144 floats
#define OFF_BTT   (OFF_THB  + 262144u)       // beta^T bf16 10112*128 = 647168 floats
#define OFF_RPART (OFF_BTT  + 647168u)       // 2528 doubles = 5056 floats (8B aligned)
#define OFF_APART (OFF_RPART + 5056u)        // 2088 doubles = 4176 floats
// total ~2.78M floats ~11.2 MB

typedef __attribute__((ext_vector_type(8))) short bf16x8;
typedef __attribute__((ext_vector_type(4))) float f32x4;

__device__ __forceinline__ float block_reduce_sum_256(float v, volatile float* sh) {
#pragma unroll
  for (int off = 32; off > 0; off >>= 1) v += __shfl_down(v, off, 64);
  __syncthreads();
  if ((threadIdx.x & 63) == 0) sh[threadIdx.x >> 6] = v;
  __syncthreads();
  return sh[0] + sh[1] + sh[2] + sh[3];
}

__device__ __forceinline__ float block_reduce_sum_1024(float v, volatile float* sh) {
#pragma unroll
  for (int off = 32; off > 0; off >>= 1) v += __shfl_down(v, off, 64);
  if ((threadIdx.x & 63) == 0) sh[threadIdx.x >> 6] = v;
  __syncthreads();
  if (threadIdx.x == 0) {
    float s = 0.f;
    for (int i = 0; i < 16; ++i) s += sh[i];
    sh[16] = s;
  }
  __syncthreads();
  float r = sh[16];
  __syncthreads();
  return r;
}

__device__ __forceinline__ float block_reduce_max_1024(float v, volatile float* sh) {
#pragma unroll
  for (int off = 32; off > 0; off >>= 1) v = fmaxf(v, __shfl_down(v, off, 64));
  if ((threadIdx.x & 63) == 0) sh[threadIdx.x >> 6] = v;
  __syncthreads();
  if (threadIdx.x == 0) {
    float m = sh[0];
    for (int i = 1; i < 16; ++i) m = fmaxf(m, sh[i]);
    sh[16] = m;
  }
  __syncthreads();
  float r = sh[16];
  __syncthreads();
  return r;
}

__device__ __forceinline__ unsigned short f2bf(float x) {
  union { float f; unsigned int u; } c; c.f = x;
  unsigned int r = c.u + 0x7FFF + ((c.u >> 16) & 1);   // RNE
  return (unsigned short)(r >> 16);
}

// ========== K1: norms (blocks 0..887) + softmaxes/zeroing (block 888) ==============
__global__ __launch_bounds__(1024)
void prep_norms_kernel(const float* __restrict__ docs, const float* __restrict__ words,
                       const float* __restrict__ topics,
                       const float* __restrict__ topic_w, const float* __restrict__ word_w,
                       float* __restrict__ nd, float* __restrict__ nw, float* __restrict__ nt,
                       float* __restrict__ b_dt, float* __restrict__ b_tw,
                       float* __restrict__ errs) {
  int tid = threadIdx.x, lane = tid & 63, wave = tid >> 6;
  if (blockIdx.x < 888) {   // row norms: 16 rows/block, one wave per row
    int row = blockIdx.x * 16 + wave;
    if (row < N_DOCS + N_WORDS + N_TOPICS) {
      const float* src; float* dst; int r;
      if (row < N_DOCS)                { src = docs;   r = row;                    dst = nd; }
      else if (row < N_DOCS + N_WORDS) { src = words;  r = row - N_DOCS;           dst = nw; }
      else                             { src = topics; r = row - N_DOCS - N_WORDS; dst = nt; }
      float s = 0.f;
#pragma unroll
      for (int k = lane; k < EDIM; k += 64) { float x = src[r * EDIM + k]; s += x * x; }
#pragma unroll
      for (int off = 32; off > 0; off >>= 1) s += __shfl_down(s, off, 64);
      if (lane == 0) dst[r] = s;
    }
    return;
  }
  // prep block
  __shared__ float sh[20];
  // topic softmax (100)
  float m = (tid < N_TOPICS) ? topic_w[tid] : -3.0e38f;
  m = block_reduce_max_1024(m, sh);
  float e = (tid < N_TOPICS) ? __expf(topic_w[tid] - m) : 0.f;
  float s = block_reduce_sum_1024(e, sh);
  if (tid < N_TOPICS) b_dt[tid] = e / s;
  // word softmax (10000), float4 vectorized
  float m2 = -3.0e38f;
  for (int i = tid * 4; i < N_WORDS; i += 4096) {
    float4 w = *reinterpret_cast<const float4*>(&word_w[i]);
    m2 = fmaxf(fmaxf(m2, fmaxf(w.x, w.y)), fmaxf(w.z, w.w));
  }
  m2 = block_reduce_max_1024(m2, sh);
  float s2 = 0.f;
  for (int i = tid * 4; i < N_WORDS; i += 4096) {
    float4 w = *reinterpret_cast<const float4*>(&word_w[i]);
    s2 += __expf(w.x - m2) + __expf(w.y - m2) + __expf(w.z - m2) + __expf(w.w - m2);
  }
  s2 = block_reduce_sum_1024(s2, sh);
  float inv2 = 1.0f / s2;
  for (int i = tid * 4; i < N_WORDS; i += 4096) {
    float4 w = *reinterpret_cast<const float4*>(&word_w[i]);
    float4 o = make_float4(__expf(w.x - m2) * inv2, __expf(w.y - m2) * inv2,
                           __expf(w.z - m2) * inv2, __expf(w.w - m2) * inv2);
    *reinterpret_cast<float4*>(&b_tw[i]) = o;
  }
  if (tid < 2) errs[tid] = 0.f;
}

// ========== K2: both distance kernels K = exp(-alpha*dist) =========================
__global__ __launch_bounds__(256)
void dist_kernel(const float* __restrict__ docs, const float* __restrict__ words,
                 const float* __restrict__ topics,
                 const float* __restrict__ nd, const float* __restrict__ nw,
                 const float* __restrict__ nt,
                 float* __restrict__ Kdt, float* __restrict__ KdtT,
                 float* __restrict__ Ktw) {
  __shared__ __align__(16) float As[16][64];
  __shared__ __align__(16) float Bs[16][64];
  const int bid = blockIdx.x;
  const float *A, *B, *nA, *nB; float *Kout, *KoutT; int nI, nJ, i0, j0; float alpha;
  if (bid < 128) {      // doc-topic: 64 i-tiles x 2 j-tiles
    A = docs; B = topics; nA = nd; nB = nt; Kout = Kdt; KoutT = KdtT;
    nI = N_DOCS; nJ = N_TOPICS; alpha = 3.0f;
    j0 = (bid & 1) * 64; i0 = (bid >> 1) * 64;
  } else {              // topic-word: 2 i-tiles x 157 j-tiles
    int b2 = bid - 128;
    A = topics; B = words; nA = nt; nB = nw; Kout = Ktw; KoutT = nullptr;
    nI = N_TOPICS; nJ = N_WORDS; alpha = 2.0f;
    i0 = (b2 & 1) * 64; j0 = (b2 >> 1) * 64;
  }
  const int tid = threadIdx.x;
  const int r = tid & 63, kg = tid >> 6;
  const int tx = tid & 15, ty = tid >> 4;
  float acc[4][4] = {};
  for (int k0 = 0; k0 < EDIM; k0 += 16) {
    float4 av = make_float4(0.f, 0.f, 0.f, 0.f);
    float4 bv = make_float4(0.f, 0.f, 0.f, 0.f);
    int gi = i0 + r, gj = j0 + r;
    if (gi < nI) av = *reinterpret_cast<const float4*>(&A[gi * EDIM + k0 + kg * 4]);
    if (gj < nJ) bv = *reinterpret_cast<const float4*>(&B[gj * EDIM + k0 + kg * 4]);
    As[kg * 4 + 0][r] = av.x; As[kg * 4 + 1][r] = av.y;
    As[kg * 4 + 2][r] = av.z; As[kg * 4 + 3][r] = av.w;
    Bs[kg * 4 + 0][r] = bv.x; Bs[kg * 4 + 1][r] = bv.y;
    Bs[kg * 4 + 2][r] = bv.z; Bs[kg * 4 + 3][r] = bv.w;
    __syncthreads();
#pragma unroll
    for (int kk = 0; kk < 16; ++kk) {
      float4 a4 = *reinterpret_cast<const float4*>(&As[kk][ty * 4]);
      float4 b4 = *reinterpret_cast<const float4*>(&Bs[kk][tx * 4]);
      float aa[4] = {a4.x, a4.y, a4.z, a4.w};
      float bb[4] = {b4.x, b4.y, b4.z, b4.w};
#pragma unroll
      for (int di = 0; di < 4; ++di)
#pragma unroll
        for (int dj = 0; dj < 4; ++dj) acc[di][dj] += aa[di] * bb[dj];
    }
    __syncthreads();
  }
#pragma unroll
  for (int di = 0; di < 4; ++di) {
    int gi = i0 + ty * 4 + di;
    if (gi < nI) {
      float na = nA[gi];
#pragma unroll
      for (int dj = 0; dj < 4; ++dj) {
        int gj = j0 + tx * 4 + dj;
        if (gj < nJ) {
          float val = __expf(-alpha * (na + nB[gj] - 2.f * acc[di][dj]));
          Kout[(size_t)gi * nJ + gj] = val;
          if (KoutT) KoutT[(size_t)gj * nI + gi] = val;
        }
      }
    }
  }
}

// ========== K3: colsum -> v for both transports ====================================
__global__ __launch_bounds__(256)
void cs_kernel(const float* __restrict__ KdtT, const float* __restrict__ b_dt,
               float* __restrict__ v_dt,
               const float* __restrict__ Ktw, const float* __restrict__ b_tw,
               float* __restrict__ v_tw) {
  __shared__ float sh[4];
  const int tid = threadIdx.x;
  if (blockIdx.x < 100) {          // DT: one block per topic column
    int j = blockIdx.x;
    float s = 0.f;
#pragma unroll 8
    for (int i = tid; i < N_DOCS; i += 256) s += KdtT[(size_t)j * N_DOCS + i];
    s = block_reduce_sum_256(s, sh);
    if (tid == 0) v_dt[j] = b_dt[j] / (s * (1.0f / N_DOCS) + 1e-16f);
  } else {                          // TW: one thread per word column
    int j = (blockIdx.x - 100) * 256 + tid;
    if (j < N_WORDS) {
      float s = 0.f;
#pragma unroll 10
      for (int i = 0; i < N_TOPICS; ++i) s += Ktw[(size_t)i * N_WORDS + j];
      v_tw[j] = b_tw[j] / (s * 0.01f + 1e-16f);
    }
  }
}

// ========== K4: rowdot -> u for both transports ====================================
__global__ __launch_bounds__(256)
void u_kernel(const float* __restrict__ Kdt, const float* __restrict__ v_dt,
              float* __restrict__ u_dt,
              const float* __restrict__ Ktw, const float* __restrict__ v_tw,
              float* __restrict__ u_tw) {
  __shared__ float vl[N_TOPICS];
  __shared__ float sh[4];
  const int tid = threadIdx.x;
  if (blockIdx.x < 16) {            // DT: one thread per doc row
    if (tid < N_TOPICS) vl[tid] = v_dt[tid];
    __syncthreads();
    int i = blockIdx.x * 256 + tid;
    float d = 0.f;
    const float* row = &Kdt[(size_t)i * N_TOPICS];
#pragma unroll
    for (int j4 = 0; j4 < N_TOPICS; j4 += 4) {
      float4 kv = *reinterpret_cast<const float4*>(&row[j4]);
      d += kv.x * vl[j4] + kv.y * vl[j4 + 1] + kv.z * vl[j4 + 2] + kv.w * vl[j4 + 3];
    }
    u_dt[i] = (1.0f / N_DOCS) / (d + 1e-16f);
  } else {                          // TW: one block per topic row
    int i = blockIdx.x - 16;
    float d = 0.f;
    const float* row = &Ktw[(size_t)i * N_WORDS];
    for (int j = tid * 4; j < N_WORDS; j += 1024) {
      float4 kv = *reinterpret_cast<const float4*>(&row[j]);
      float4 vv = *reinterpret_cast<const float4*>(&v_tw[j]);
      d += kv.x * vv.x + kv.y * vv.y + kv.z * vv.z + kv.w * vv.w;
    }
    d = block_reduce_sum_256(d, sh);
    if (tid == 0) u_tw[i] = 0.01f / (d + 1e-16f);
  }
}

// ========== K5: convergence error for both transports ==============================
__global__ __launch_bounds__(256)
void err_kernel(const float* __restrict__ KdtT, const float* __restrict__ u_dt,
                const float* __restrict__ v_dt, const float* __restrict__ b_dt,
                const float* __restrict__ Ktw, const float* __restrict__ u_tw,
                const float* __restrict__ v_tw, const float* __restrict__ b_tw,
                float* __restrict__ errs) {
  __shared__ float sh[4];
  __shared__ float ul[N_TOPICS];
  const int tid = threadIdx.x;
  if (blockIdx.x < 100) {
    int j = blockIdx.x;
    float s = 0.f;
#pragma unroll 8
    for (int i = tid; i < N_DOCS; i += 256) s += KdtT[(size_t)j * N_DOCS + i] * u_dt[i];
    s = block_reduce_sum_256(s, sh);
    if (tid == 0) atomicAdd(&errs[0], fabsf(v_dt[j] * s - b_dt[j]));
  } else {
    if (tid < N_TOPICS) ul[tid] = u_tw[tid];
    __syncthreads();
    int j = (blockIdx.x - 100) * 256 + tid;
    float e = 0.f;
    if (j < N_WORDS) {
      float s = 0.f;
#pragma unroll 10
      for (int i = 0; i < N_TOPICS; ++i) s += Ktw[(size_t)i * N_WORDS + j] * ul[i];
      e = fabsf(v_tw[j] * s - b_tw[j]);
    }
    e = block_reduce_sum_256(e, sh);
    if (tid == 0) atomicAdd(&errs[1], e);
  }
}

// ========== K6: faithful remainder loops (exit immediately when converged) =========
__global__ __launch_bounds__(1024)
void rem_kernel(const float* __restrict__ Kdt, const float* __restrict__ KdtT,
                const float* __restrict__ b_dt, float* __restrict__ u_dt,
                float* __restrict__ v_dt,
                const float* __restrict__ Ktw, const float* __restrict__ b_tw,
                float* __restrict__ u_tw, float* __restrict__ v_tw,
                const float* __restrict__ errs) {
  __shared__ float rsm[20104];     // 80.4 KB, partitioned per branch
  const int tid = threadIdx.x, wave = tid >> 6, lane = tid & 63;
  if (blockIdx.x == 0) {           // DT remainder
    float err = errs[0];
    if (!(err > 0.005f)) return;
    float* u_l = rsm; float* v_l = rsm + 4096; float* bl = rsm + 4196; float* esh = rsm + 4296;
    for (int i = tid; i < N_DOCS; i += 1024) u_l[i] = u_dt[i];
    if (tid < N_TOPICS) { bl[tid] = b_dt[tid]; v_l[tid] = v_dt[tid]; }
    __syncthreads();
    int cpt = 1;
    while (err > 0.005f && cpt < 5000) {
      for (int j = wave; j < N_TOPICS; j += 16) {
        float s = 0.f;
        for (int i = lane; i < N_DOCS; i += 64) s += KdtT[(size_t)j * N_DOCS + i] * u_l[i];
#pragma unroll
        for (int off = 32; off > 0; off >>= 1) s += __shfl_down(s, off, 64);
        if (lane == 0) v_l[j] = bl[j] / (s + 1e-16f);
      }
      __syncthreads();
      for (int i = tid; i < N_DOCS; i += 1024) {
        float d = 0.f;
        for (int j = 0; j < N_TOPICS; ++j) d += Kdt[(size_t)i * N_TOPICS + j] * v_l[j];
        u_l[i] = (1.0f / N_DOCS) / (d + 1e-16f);
      }
      __syncthreads();
      ++cpt;
      if (cpt % 50 == 1) {
        if (tid == 0) *esh = 0.f;
        __syncthreads();
        for (int j = wave; j < N_TOPICS; j += 16) {
          float s = 0.f;
          for (int i = lane; i < N_DOCS; i += 64) s += KdtT[(size_t)j * N_DOCS + i] * u_l[i];
#pragma unroll
          for (int off = 32; off > 0; off >>= 1) s += __shfl_down(s, off, 64);
          if (lane == 0) atomicAdd(esh, fabsf(v_l[j] * s - bl[j]));
        }
        __syncthreads();
        err = *esh;
        __syncthreads();
      }
    }
    for (int i = tid; i < N_DOCS; i += 1024) u_dt[i] = u_l[i];
    if (tid < N_TOPICS) v_dt[tid] = v_l[tid];
  } else {                          // TW remainder
    float err = errs[1];
    if (!(err > 0.005f)) return;
    float* v_l = rsm; float* bl = rsm + 10000; float* u_l = rsm + 20000; float* esh = rsm + 20100;
    for (int j = tid; j < N_WORDS; j += 1024) { v_l[j] = v_tw[j]; bl[j] = b_tw[j]; }
    if (tid < N_TOPICS) u_l[tid] = u_tw[tid];
    __syncthreads();
    int cpt = 1;
    while (err > 0.005f && cpt < 5000) {
      for (int j = tid; j < N_WORDS; j += 1024) {
        float s = 0.f;
        for (int i = 0; i < N_TOPICS; ++i) s += Ktw[(size_t)i * N_WORDS + j] * u_l[i];
        v_l[j] = bl[j] / (s + 1e-16f);
      }
      __syncthreads();
      for (int i = wave; i < N_TOPICS; i += 16) {
        float s = 0.f;
        for (int j = lane; j < N_WORDS; j += 64) s += Ktw[(size_t)i * N_WORDS + j] * v_l[j];
#pragma unroll
        for (int off = 32; off > 0; off >>= 1) s += __shfl_down(s, off, 64);
        if (lane == 0) u_l[i] = 0.01f / (s + 1e-16f);
      }
      __syncthreads();
      ++cpt;
      if (cpt % 50 == 1) {
        if (tid == 0) *esh = 0.f;
        __syncthreads();
        float e = 0.f;
        for (int j = tid; j < N_WORDS; j += 1024) {
          float s = 0.f;
          for (int i = 0; i < N_TOPICS; ++i) s += Ktw[(size_t)i * N_WORDS + j] * u_l[i];
          e += fabsf(v_l[j] * s - bl[j]);
        }
        atomicAdd(esh, e);
        __syncthreads();
        err = *esh;
        __syncthreads();
      }
    }
    for (int j = tid; j < N_WORDS; j += 1024) v_tw[j] = v_l[j];
    if (tid < N_TOPICS) u_tw[tid] = u_l[tid];
  }
}

// ========== K7: theta/beta^T (bf16, K-padded) + transport losses (per-block slot) ==
__global__ __launch_bounds__(256)
void apply_kernel(const float* __restrict__ Kdt, const float* __restrict__ u_dt,
                  const float* __restrict__ v_dt,
                  const float* __restrict__ Ktw, const float* __restrict__ u_tw,
                  const float* __restrict__ v_tw,
                  unsigned short* __restrict__ theta_b, unsigned short* __restrict__ beta_bT,
                  double* __restrict__ apart) {
  __shared__ float sh[4];
  __shared__ float ul[N_TOPICS];
  const int tid = threadIdx.x;
  float lp = 0.f;
  if (blockIdx.x < 2048) {          // theta: 4096*128 elements, loss scaled by 1/3
    int idx = blockIdx.x * 256 + tid;
    int i = idx >> 7, k = idx & 127;
    unsigned short o = 0;
    if (k < N_TOPICS) {
      float kv = Kdt[(size_t)i * N_TOPICS + k];
      float t = u_dt[i] * kv * v_dt[k];
      lp = t * (-__logf(kv) * (1.0f / 3.0f));
      o = f2bf(t * (float)N_DOCS);
    }
    theta_b[idx] = o;
  } else {                          // beta^T rows, loss scaled by 1/2
    if (tid < N_TOPICS) ul[tid] = u_tw[tid];
    __syncthreads();
    int n = (blockIdx.x - 2048) * 256 + tid;
    if (n < N_WORDS) {
      float vn = v_tw[n];
      unsigned short* dst = &beta_bT[(size_t)n * KPAD];
#pragma unroll 2
      for (int kc = 0; kc < KPAD; kc += 8) {
        unsigned short pk[8];
#pragma unroll
        for (int q = 0; q < 8; ++q) {
          int k = kc + q;
          unsigned short o = 0;
          if (k < N_TOPICS) {
            float kv = Ktw[(size_t)k * N_WORDS + n];
            float t = ul[k] * kv * vn;
            lp += t * (-__logf(kv) * 0.5f);
            o = f2bf(t * (float)N_TOPICS);
          }
          pk[q] = o;
        }
        *(uint4*)&dst[kc] = *(uint4*)pk;
      }
    } else if (n < BT_ROWS) {       // zero the pad rows so recon stays clean
      unsigned short* dst = &beta_bT[(size_t)n * KPAD];
      uint4 z = make_uint4(0, 0, 0, 0);
#pragma unroll
      for (int kc = 0; kc < KPAD; kc += 8) *(uint4*)&dst[kc] = z;
    }
  }
  lp = block_reduce_sum_256(lp, sh);
  if (tid == 0) apart[blockIdx.x] = (double)lp;   // distinct slot: no atomics
}

// ========== K8: recon via bf16 MFMA; per-block partial to distinct slot ============
#define AS_LD 136   // staging LD (bf16): 2-way conflicts only
#define CLD   132   // acc tile LD (fp32): float4-aligned
__global__ __launch_bounds__(256, 2)
void recon_kernel(const unsigned short* __restrict__ theta_b,
                  const unsigned short* __restrict__ beta_bT,
                  const float* __restrict__ bow, double* __restrict__ rpart) {
  __shared__ __align__(16) char smem[128 * AS_LD * 2 * 2];  // 69632 B, reused for C tile
  __shared__ float sh4[4];
  unsigned short* As = (unsigned short*)smem;
  unsigned short* Bs = As + 128 * AS_LD;
  float* C = (float*)smem;          // 128 x CLD fp32 = 67584 B <= 69632
  const int tid = threadIdx.x;
  const int c0 = blockIdx.x * 128, r0 = blockIdx.y * 128;

  // ---- stage theta/beta tiles into LDS ----
#pragma unroll
  for (int pass = 0; pass < 8; ++pass) {
    int idx = pass * 256 + tid;     // 0..2047
    int r = idx >> 4, k16 = idx & 15;
    *(uint4*)&As[r * AS_LD + k16 * 8] = *(const uint4*)&theta_b[(size_t)(r0 + r) * KPAD + k16 * 8];
    *(uint4*)&Bs[r * AS_LD + k16 * 8] = *(const uint4*)&beta_bT[(size_t)(c0 + r) * KPAD + k16 * 8];
  }
  __syncthreads();

  // ---- MFMA: 128x128 tile, 4 waves, 4x4 fragments each ----
  const int wave = tid >> 6, lane = tid & 63;
  const int wr = (wave >> 1) * 64, wc = (wave & 1) * 64;
  const int lm = lane & 15, q = lane >> 4;
  f32x4 acc[4][4] = {};
#pragma unroll
  for (int kc = 0; kc < 4; ++kc) {
    int k = kc * 32 + q * 8;
    bf16x8 af[4], bfr[4];
#pragma unroll
    for (int t = 0; t < 4; ++t) {
      af[t]  = *(const bf16x8*)&As[(wr + t * 16 + lm) * AS_LD + k];
      bfr[t] = *(const bf16x8*)&Bs[(wc + t * 16 + lm) * AS_LD + k];
    }
#pragma unroll
    for (int mi = 0; mi < 4; ++mi)
#pragma unroll
      for (int ni = 0; ni < 4; ++ni)
        acc[mi][ni] = __builtin_amdgcn_mfma_f32_16x16x32_bf16(af[mi], bfr[ni],
                                                              acc[mi][ni], 0, 0, 0);
  }
  __syncthreads();                  // A/B consumed; reuse smem for C tile

  // ---- scatter acc (MFMA C layout) into fp32 LDS tile ----
#pragma unroll
  for (int mi = 0; mi < 4; ++mi)
#pragma unroll
    for (int ni = 0; ni < 4; ++ni)
#pragma unroll
      for (int reg = 0; reg < 4; ++reg) {
        int row = wr + mi * 16 + q * 4 + reg;
        int col = wc + ni * 16 + lm;
        C[row * CLD + col] = acc[mi][ni][reg];
      }
  __syncthreads();

  // ---- coalesced bow read + log/dot epilogue ----
  float lp = 0.f;
  const int c4 = tid & 31;          // float4 column 0..31
  const int rb = tid >> 5;          // row base 0..7
  const int gj0 = c0 + c4 * 4;
  if (gj0 < N_WORDS) {              // N_WORDS%4==0 -> full float4 valid when true
#pragma unroll
    for (int it = 0; it < 16; ++it) {
      int row = rb + it * 8;
      float4 bw = *reinterpret_cast<const float4*>(&bow[(size_t)(r0 + row) * N_WORDS + gj0]);
      float4 rc = *reinterpret_cast<const float4*>(&C[row * CLD + c4 * 4]);
      lp += bw.x * __logf(rc.x + 1e-12f) + bw.y * __logf(rc.y + 1e-12f)
          + bw.z * __logf(rc.z + 1e-12f) + bw.w * __logf(rc.w + 1e-12f);
    }
  }
  lp = block_reduce_sum_256(lp, sh4);
  if (tid == 0) rpart[blockIdx.y * 79 + blockIdx.x] = (double)lp;  // distinct slot
}

// ========== K9: final reduce over all partials -> scalar out =======================
__global__ __launch_bounds__(1024)
void finalize_kernel(const double* __restrict__ rpart, const double* __restrict__ apart,
                     float* __restrict__ out) {
  __shared__ double sh[17];
  const int tid = threadIdx.x, lane = tid & 63;
  double s2 = 0.0, s01 = 0.0;
  for (int i = tid; i < RECON_BLOCKS; i += 1024) s2 += rpart[i];
  for (int i = tid; i < APPLY_BLOCKS; i += 1024) s01 += apart[i];
  double t = s01 - s2 * (1.0 / N_DOCS);
#pragma unroll
  for (int off = 32; off > 0; off >>= 1) t += __shfl_down(t, off, 64);
  if (lane == 0) sh[tid >> 6] = t;
  __syncthreads();
  if (tid == 0) {
    double s = 0.0;
    for (int i = 0; i < 16; ++i) s += sh[i];
    out[0] = (float)s;
  }
}

extern "C" void kernel_launch(void* const* d_in, const int* in_sizes, int n_in,
                              void* d_out, int out_size, void* d_ws, size_t ws_size,
                              hipStream_t stream) {
  const float* bow     = (const float*)d_in[0];
  const float* docs    = (const float*)d_in[1];
  const float* words   = (const float*)d_in[2];
  const float* topics  = (const float*)d_in[3];
  const float* word_w  = (const float*)d_in[4];
  const float* topic_w = (const float*)d_in[5];
  float* out = (float*)d_out;

  float* fws  = (float*)d_ws;
  float* errs = fws + 8;
  float* Kdt  = fws + OFF_KDT;
  float* KdtT = fws + OFF_KDTT;
  float* Ktw  = fws + OFF_KTW;
  float* b_dt = fws + OFF_BDT;
  float* b_tw = fws + OFF_BTW;
  float* nd   = fws + OFF_ND;
  float* nw   = fws + OFF_NW;
  float* nt   = fws + OFF_NT;
  float* u_dt = fws + OFF_UDT;
  float* v_dt = fws + OFF_VDT;
  float* u_tw = fws + OFF_UTW;
  float* v_tw = fws + OFF_VTW;
  unsigned short* theta_b = (unsigned short*)(fws + OFF_THB);
  unsigned short* beta_bT = (unsigned short*)(fws + OFF_BTT);
  double* rpart = (double*)(fws + OFF_RPART);
  double* apart = (double*)(fws + OFF_APART);

  prep_norms_kernel<<<dim3(889), dim3(1024), 0, stream>>>(
      docs, words, topics, topic_w, word_w, nd, nw, nt, b_dt, b_tw, errs);
  dist_kernel<<<dim3(442), dim3(256), 0, stream>>>(
      docs, words, topics, nd, nw, nt, Kdt, KdtT, Ktw);
  cs_kernel<<<dim3(140), dim3(256), 0, stream>>>(KdtT, b_dt, v_dt, Ktw, b_tw, v_tw);
  u_kernel<<<dim3(116), dim3(256), 0, stream>>>(Kdt, v_dt, u_dt, Ktw, v_tw, u_tw);
  err_kernel<<<dim3(140), dim3(256), 0, stream>>>(
      KdtT, u_dt, v_dt, b_dt, Ktw, u_tw, v_tw, b_tw, errs);
  rem_kernel<<<dim3(2), dim3(1024), 0, stream>>>(
      Kdt, KdtT, b_dt, u_dt, v_dt, Ktw, b_tw, u_tw, v_tw, errs);
  apply_kernel<<<dim3(APPLY_BLOCKS), dim3(256), 0, stream>>>(
      Kdt, u_dt, v_dt, Ktw, u_tw, v_tw, theta_b, beta_bT, apart);
  recon_kernel<<<dim3(79, 32), dim3(256), 0, stream>>>(theta_b, beta_bT, bow, rpart);
  finalize_kernel<<<dim3(1), dim3(1024), 0, stream>>>(rpart, apart, out);

  (void)in_sizes; (void)n_in; (void)out_size; (void)ws_size;
}